// Round 9
// baseline (197.867 us; speedup 1.0000x reference)
//
#include <hip/hip_runtime.h>
#include <hip/hip_bf16.h>

// MHA forward. Inputs fp32, output fp32, compute bf16 MFMA w/ fp32 accum.
// B=8, N=1024, DIM=768, NH=12, HD=64, M=8192.
// R20: T3-minimal pipelined 2-phase GEMMs. Keep BK=32 / 4 gloads per step
// (R13/R16/R18/R19 law: any VGPR/complexity growth loses via occupancy),
// but LDS-double-buffer with stage(t+1) BEFORE compute(t) and ONE barrier
// per step: loads for t+1 fly under t's ds_reads+MFMAs (in-wave overlap,
// catalog T3 "minimum 2-phase", 682 TF same-probe vs our 604-class).
// Buffer toggle is wave-uniform ((kt&1)<<12 -> SGPR). LDS 16->32KB
// (5 blocks/CU, 20 waves vs 24 -- the measured risk).
// R19 refuted: barrier COUNT is not the lever (BK=64 panels: VGPR 96,
// 62us). R17 carried: fused prep, vtrans separate, R11-exact epilogues.
// R14 carried (attn): double-buffered K/V reusing dead Q LDS region, 1
// barrier/KV-tile, 2 prefetch reg sets (T14), setprio around MFMA (T5).
// R11 carried: 512-thread attn, bare v_exp_f32, S^T operand swap + sigma
// permutation, XCD swizzle bh=bx%96, deferred l-reduction, V pre-transposed.
// WS high-water 55,050,240 B (proven available).

typedef __bf16 bf16x8 __attribute__((ext_vector_type(8)));
typedef float f32x4 __attribute__((ext_vector_type(4)));

#define MFMA16(a, b, c) __builtin_amdgcn_mfma_f32_16x16x32_bf16(a, b, c, 0, 0, 0)

#if defined(__has_builtin) && __has_builtin(__builtin_amdgcn_exp2f)
#define EXP2(x) __builtin_amdgcn_exp2f(x)
#else
#define EXP2(x) exp2f(x)
#endif

__device__ inline __bf16 to_bf16(float f) {
  __hip_bfloat16 h = __float2bfloat16(f);
  return *reinterpret_cast<__bf16*>(&h);
}

// Direct global->LDS DMA, 16B per lane. LDS dest is wave-uniform base + lane*16.
__device__ __forceinline__ void gload16(const void* g, void* l) {
  __builtin_amdgcn_global_load_lds(
      (const __attribute__((address_space(1))) unsigned int*)(unsigned long long)g,
      (__attribute__((address_space(3))) unsigned int*)(unsigned long long)l,
      16, 0, 0);
}

// ---------------------------------------------------------------- diagnostic
__global__ void ws_diag_kernel(float* out, int n, float val) {
  int i = blockIdx.x * 256 + threadIdx.x;
  if (i < n) out[i] = val;
}

// ---------------------------------------------------------------- fused prep
// blocks [0,3072): x fp32 -> xc bf16 (8 elems/thread)
// blocks [3072,4800): Wqkv [768][2304] -> WqkvT [2304][768] bf16 (72x24 tiles)
// blocks [4800,5376): Wproj [768][768] -> WprojT [768][768] bf16 (24x24 tiles)
__global__ __launch_bounds__(256) void prep_kernel(
    const float* __restrict__ x, __hip_bfloat16* __restrict__ xc,
    const float* __restrict__ Wqkv, __hip_bfloat16* __restrict__ WqkvT,
    const float* __restrict__ Wproj, __hip_bfloat16* __restrict__ WprojT) {
  __shared__ __hip_bfloat16 tile[32][33];
  const int b = blockIdx.x;
  if (b < 3072) {
    int i = b * 256 + threadIdx.x;
    float4 a = ((const float4*)x)[i * 2], c = ((const float4*)x)[i * 2 + 1];
    __hip_bfloat16 o[8] = {__float2bfloat16(a.x), __float2bfloat16(a.y),
                           __float2bfloat16(a.z), __float2bfloat16(a.w),
                           __float2bfloat16(c.x), __float2bfloat16(c.y),
                           __float2bfloat16(c.z), __float2bfloat16(c.w)};
    *(int4*)(xc + (size_t)i * 8) = *(const int4*)o;
    return;
  }
  const float* W;
  __hip_bfloat16* Wt;
  int rows, cols, bx, by;
  if (b < 4800) {
    int idx = b - 3072;  // 72 x 24 tile grid
    W = Wqkv; Wt = WqkvT; rows = 768; cols = 2304;
    bx = idx % 72; by = idx / 72;
  } else {
    int idx = b - 4800;  // 24 x 24 tile grid
    W = Wproj; Wt = WprojT; rows = 768; cols = 768;
    bx = idx % 24; by = idx / 24;
  }
  const int tc = bx * 32, tr = by * 32;
  const int tx = threadIdx.x & 31, ty = threadIdx.x >> 5;  // (32,8)
#pragma unroll
  for (int i = 0; i < 4; ++i) {
    int r = ty + i * 8;
    tile[r][tx] = __float2bfloat16(W[(size_t)(tr + r) * cols + tc + tx]);
  }
  __syncthreads();
#pragma unroll
  for (int i = 0; i < 4; ++i) {
    int r = ty + i * 8;
    Wt[(size_t)(tc + r) * rows + tr + tx] = tile[tx][r];
  }
}

// ---------------------------------------------------------------- V transpose
// Vrow [96][1024][64] -> Vt [96][64][1024]. 64x64 bf16 tile per block.
__global__ __launch_bounds__(256) void vtrans_kernel(
    const __hip_bfloat16* __restrict__ Vrow, __hip_bfloat16* __restrict__ Vt) {
  constexpr int LP = 72;
  __shared__ __bf16 tile[64 * LP];
  const int tid = threadIdx.x;
  const int bh = blockIdx.x;
  const int n0 = blockIdx.y * 64;
  const size_t base = (size_t)bh << 16;
#pragma unroll
  for (int i = 0; i < 2; ++i) {
    int s = tid + 256 * i;
    int r = s >> 3, c8 = (s & 7) * 8;
    *(int4*)(&tile[r * LP + c8]) =
        *(const int4*)(Vrow + base + (size_t)(n0 + r) * 64 + c8);
  }
  __syncthreads();
#pragma unroll
  for (int i = 0; i < 2; ++i) {
    int s = tid + 256 * i;
    int d = s >> 3, n8 = (s & 7) * 8;
    __bf16 o[8];
#pragma unroll
    for (int j = 0; j < 8; ++j) o[j] = tile[(n8 + j) * LP + d];
    *(int4*)(Vt + base + ((size_t)d << 10) + n0 + n8) = *(const int4*)o;
  }
}

// ---------------------------------------------------------------- GEMM common
constexpr int GK = 768;

// ---------------------------------------------------------------- QKV GEMM
// 128x128 tile, BK=32, 4 waves. LDS double-buffered (2x16KB): per K-step,
// issue stage(t+1) gloads, compute t, ONE barrier (drains t+1's loads).
__global__ __launch_bounds__(256) void gemm_qkv_kernel(
    const __hip_bfloat16* __restrict__ A,    // xc bf16 [8192][768]
    const __hip_bfloat16* __restrict__ Bt,   // WqkvT [2304][768] bf16
    const float* __restrict__ bias,          // b_qkv fp32 [2304]
    __hip_bfloat16* __restrict__ Qw,         // [96][1024][64] (Q scaled log2e/8)
    __hip_bfloat16* __restrict__ Kw,         // [96][1024][64]
    __hip_bfloat16* __restrict__ Vw) {       // [96][1024][64] row-major
  __shared__ __align__(16) __bf16 As[2 * 4096];  // half h at +h*4096
  __shared__ __align__(16) __bf16 Bs[2 * 4096];
  const int tid = threadIdx.x;
  const int lane = tid & 63, wave = tid >> 6;
  const int wr = wave >> 1, wc = wave & 1;
  const int m0 = blockIdx.x * 128, n0 = blockIdx.y * 128;
  const int fr = lane & 15, q4 = lane >> 4;

  const int r4 = lane >> 2, c8 = (lane & 3) * 8;
  const __hip_bfloat16* ga0 = A + (size_t)(m0 + wave * 32 + r4) * GK + c8;
  const __hip_bfloat16* gb0 = Bt + (size_t)(n0 + wave * 32 + r4) * GK + c8;
  __bf16* la0 = &As[wave * 1024];
  __bf16* lb0 = &Bs[wave * 1024];

  f32x4 acc[4][4] = {};

  // prologue: stage tile 0 into half 0
  gload16(ga0, la0);
  gload16(ga0 + 16 * GK, la0 + 512);
  gload16(gb0, lb0);
  gload16(gb0 + 16 * GK, lb0 + 512);
  __syncthreads();

  for (int kt = 0; kt < GK / 32; ++kt) {
    const int cur = (kt & 1) << 12;   // current half (elems)
    const int nxt = 4096 - cur;       // staging half
    if (kt + 1 < GK / 32) {           // issue next tile's loads first
      gload16(ga0 + (kt + 1) * 32, la0 + nxt);
      gload16(ga0 + (kt + 1) * 32 + 16 * GK, la0 + nxt + 512);
      gload16(gb0 + (kt + 1) * 32, lb0 + nxt);
      gload16(gb0 + (kt + 1) * 32 + 16 * GK, lb0 + nxt + 512);
    }
    bf16x8 af[4], bfr[4];
#pragma unroll
    for (int i = 0; i < 4; ++i)
      af[i] = *(const bf16x8*)(&As[cur + (wr * 64 + i * 16 + fr) * 32 + q4 * 8]);
#pragma unroll
    for (int j = 0; j < 4; ++j)
      bfr[j] = *(const bf16x8*)(&Bs[cur + (wc * 64 + j * 16 + fr) * 32 + q4 * 8]);
#pragma unroll
    for (int i = 0; i < 4; ++i)
#pragma unroll
      for (int j = 0; j < 4; ++j)
        acc[i][j] = MFMA16(af[i], bfr[j], acc[i][j]);
    __syncthreads();  // drains next-tile loads; orders reads vs next stage
  }

#pragma unroll
  for (int j = 0; j < 4; ++j) {
    int col = n0 + wc * 64 + j * 16 + fr;
    int which = col / 768;
    int rem = col - which * 768;
    int h = rem >> 6, d = rem & 63;
    float bv = bias[col];
    __hip_bfloat16* dst = (which == 0) ? Qw : (which == 1) ? Kw : Vw;
    // Q scale = 1/sqrt(64) * log2(e), so attention can use raw exp2.
    float scale = (which == 0) ? 0.18033688011112042f : 1.0f;
#pragma unroll
    for (int i = 0; i < 4; ++i) {
#pragma unroll
      for (int r = 0; r < 4; ++r) {
        int row = m0 + wr * 64 + i * 16 + q4 * 4 + r;
        int bb = row >> 10, nn = row & 1023;
        float v = (acc[i][j][r] + bv) * scale;
        dst[(((size_t)(bb * 12 + h) * 1024 + nn) << 6) + d] = __float2bfloat16(v);
      }
    }
  }
}

// ---------------------------------------------------------------- proj GEMM
__global__ __launch_bounds__(256) void gemm_proj_kernel(
    const __hip_bfloat16* __restrict__ A,   // attnO bf16 [8192][768]
    const __hip_bfloat16* __restrict__ Bt,  // WprojT bf16 [768][768]
    const float* __restrict__ bias,         // b_proj fp32 [768]
    float* __restrict__ out) {              // d_out fp32 [8192][768]
  __shared__ __align__(16) __bf16 As[2 * 4096];
  __shared__ __align__(16) __bf16 Bs[2 * 4096];
  const int tid = threadIdx.x;
  const int lane = tid & 63, wave = tid >> 6;
  const int wr = wave >> 1, wc = wave & 1;
  const int m0 = blockIdx.x * 128, n0 = blockIdx.y * 128;
  const int fr = lane & 15, q4 = lane >> 4;

  const int r4 = lane >> 2, c8 = (lane & 3) * 8;
  const __hip_bfloat16* ga0 = A + (size_t)(m0 + wave * 32 + r4) * GK + c8;
  const __hip_bfloat16* gb0 = Bt + (size_t)(n0 + wave * 32 + r4) * GK + c8;
  __bf16* la0 = &As[wave * 1024];
  __bf16* lb0 = &Bs[wave * 1024];

  f32x4 acc[4][4] = {};

  gload16(ga0, la0);
  gload16(ga0 + 16 * GK, la0 + 512);
  gload16(gb0, lb0);
  gload16(gb0 + 16 * GK, lb0 + 512);
  __syncthreads();

  for (int kt = 0; kt < GK / 32; ++kt) {
    const int cur = (kt & 1) << 12;
    const int nxt = 4096 - cur;
    if (kt + 1 < GK / 32) {
      gload16(ga0 + (kt + 1) * 32, la0 + nxt);
      gload16(ga0 + (kt + 1) * 32 + 16 * GK, la0 + nxt + 512);
      gload16(gb0 + (kt + 1) * 32, lb0 + nxt);
      gload16(gb0 + (kt + 1) * 32 + 16 * GK, lb0 + nxt + 512);
    }
    bf16x8 af[4], bfr[4];
#pragma unroll
    for (int i = 0; i < 4; ++i)
      af[i] = *(const bf16x8*)(&As[cur + (wr * 64 + i * 16 + fr) * 32 + q4 * 8]);
#pragma unroll
    for (int j = 0; j < 4; ++j)
      bfr[j] = *(const bf16x8*)(&Bs[cur + (wc * 64 + j * 16 + fr) * 32 + q4 * 8]);
#pragma unroll
    for (int i = 0; i < 4; ++i)
#pragma unroll
      for (int j = 0; j < 4; ++j)
        acc[i][j] = MFMA16(af[i], bfr[j], acc[i][j]);
    __syncthreads();
  }

#pragma unroll
  for (int j = 0; j < 4; ++j) {
    int col = n0 + wc * 64 + j * 16 + fr;
    float bv = bias[col];
#pragma unroll
    for (int i = 0; i < 4; ++i) {
#pragma unroll
      for (int r = 0; r < 4; ++r) {
        int row = m0 + wr * 64 + i * 16 + q4 * 4 + r;
        out[(size_t)row * 768 + col] = acc[i][j][r] + bv;
      }
    }
  }
}

// ---------------------------------------------------------------- attention
// block = (b,h,128 q-rows); 8 waves x 16 qrows; KV tiles of 64 keys.
// S^T = K.Q^T via operand swap; P stays in registers (sigma key permutation
// shared by P regs and V LDS layout). XCD swizzle bh=bx%96.
// K/V double-buffered; buf1 reuses the dead Q staging region. One barrier
// per KV tile; two prefetch register sets (T14); setprio around MFMA (T5).
__global__ __launch_bounds__(512) void attn_kernel(
    const __hip_bfloat16* __restrict__ Qw,  // [96][1024][64], scaled log2e/8
    const __hip_bfloat16* __restrict__ Kw,  // [96][1024][64]
    const __hip_bfloat16* __restrict__ Vt,  // [96][64][1024]
    __hip_bfloat16* __restrict__ O) {       // attnO [8192][768], col = h*64+d
  constexpr int LP = 72;
  // [0,9216): Q staging, then buf1 {K1@0, V1@4608}
  // [9216,18432): buf0 {K0@9216, V0@13824}
  __shared__ __bf16 smem[18432];
  __bf16* Qs = smem;
  __bf16* K1 = smem;
  __bf16* V1 = smem + 4608;
  __bf16* K0 = smem + 9216;
  __bf16* V0 = smem + 13824;
  const int tid = threadIdx.x;
  const int lane = tid & 63, wave = tid >> 6;  // 8 waves
  const int fr = lane & 15, q4 = lane >> 4;
  const int bh = blockIdx.x % 96, qt = blockIdx.x / 96;  // XCD-local KV
  const __hip_bfloat16* Qb = Qw + ((size_t)bh * 1024 + qt * 128) * 64;
  const __hip_bfloat16* Kb = Kw + (size_t)bh * 65536;
  const __hip_bfloat16* Vb = Vt + (size_t)bh * 65536;

  // deep prefetch: tile 0 into reg set A
  const int krow = tid >> 3, kc = (tid & 7) * 8;
  int4 kregA = *(const int4*)(Kb + (size_t)krow * 64 + kc);
  int4 vregA = *(const int4*)(Vb + ((size_t)krow << 10) + kc);

  // stage Q 128x64 (2 int4/thread)
#pragma unroll
  for (int i = 0; i < 2; ++i) {
    int s = tid + 512 * i;
    int row = s >> 3, c = (s & 7) * 8;
    *(int4*)(&Qs[row * LP + c]) = *(const int4*)(Qb + row * 64 + c);
  }
  __syncthreads();
  bf16x8 qf[2];
#pragma unroll
  for (int ks = 0; ks < 2; ++ks)
    qf[ks] = *(const bf16x8*)(&Qs[(wave * 16 + fr) * LP + ks * 32 + q4 * 8]);

  float l_i = 0.f;        // per-lane partial over this lane's 16 keys/iter
  f32x4 accO[4] = {};     // C-layout: row=qrow(q4*4+r), col=d(dt*16+fr)

  // sigma destination base for V staging (lane-constant)
  const int sc8 = tid & 7;  // which 8-key chunk this thread stages
  const int sbase = ((sc8 >> 2) << 5) | ((sc8 & 1) << 4) | (((sc8 >> 1) & 1) << 2);

  // prolog: write buf0 <- tile 0; prefetch tile 1 into reg set B
  *(int4*)(&K0[krow * LP + kc]) = kregA;
  *(int2*)(&V0[krow * LP + sbase]) = make_int2(vregA.x, vregA.y);
  *(int2*)(&V0[krow * LP + sbase + 8]) = make_int2(vregA.z, vregA.w);
  int4 kregB = *(const int4*)(Kb + (size_t)(64 + krow) * 64 + kc);
  int4 vregB = *(const int4*)(Vb + ((size_t)krow << 10) + 64 + kc);
  __syncthreads();  // buf0 ready; all qf reads done -> Q region free

  auto compute_tile = [&](const __bf16* Kbuf, const __bf16* Vbuf) {
    // S^T = K.Q^T: scT[nt][r] = P[qrow=wave*16+fr][key=nt*16+q4*4+r]
    f32x4 scT[4];
    __builtin_amdgcn_s_setprio(1);
#pragma unroll
    for (int nt = 0; nt < 4; ++nt) {
      bf16x8 kf0 = *(const bf16x8*)(&Kbuf[(nt * 16 + fr) * LP + q4 * 8]);
      bf16x8 kf1 = *(const bf16x8*)(&Kbuf[(nt * 16 + fr) * LP + 32 + q4 * 8]);
      f32x4 z = {};
      z = MFMA16(kf0, qf[0], z);
      scT[nt] = MFMA16(kf1, qf[1], z);
    }
    __builtin_amdgcn_s_setprio(0);
    // p = 2^s (bare v_exp_f32); per-lane l partial
    float rs = 0.f;
#pragma unroll
    for (int nt = 0; nt < 4; ++nt)
#pragma unroll
      for (int r = 0; r < 4; ++r) {
        float p = EXP2(scT[nt][r]);
        scT[nt][r] = p;
        rs += p;
      }
    l_i += rs;
    // O += P.V — P A-fragments are this lane's own registers under sigma
#pragma unroll
    for (int ks = 0; ks < 2; ++ks) {
      bf16x8 pf;
#pragma unroll
      for (int e = 0; e < 4; ++e) {
        pf[e] = to_bf16(scT[2 * ks][e]);
        pf[4 + e] = to_bf16(scT[2 * ks + 1][e]);
      }
      __builtin_amdgcn_s_setprio(1);
#pragma unroll
      for (int dt = 0; dt < 4; ++dt) {
        bf16x8 vf = *(const bf16x8*)(&Vbuf[(dt * 16 + fr) * LP + ks * 32 + q4 * 8]);
        accO[dt] = MFMA16(pf, vf, accO[dt]);
      }
      __builtin_amdgcn_s_setprio(0);
    }
  };

  for (int kt2 = 0; kt2 < 16; kt2 += 2) {
    // even phase: compute tile kt2 from buf0; stage kt2+1 -> buf1;
    // prefetch kt2+2 -> reg set A
    compute_tile(K0, V0);
    *(int4*)(&K1[krow * LP + kc]) = kregB;
    *(int2*)(&V1[krow * LP + sbase]) = make_int2(vregB.x, vregB.y);
    *(int2*)(&V1[krow * LP + sbase + 8]) = make_int2(vregB.z, vregB.w);
    if (kt2 + 2 < 16) {
      kregA = *(const int4*)(Kb + (size_t)((kt2 + 2) * 64 + krow) * 64 + kc);
      vregA = *(const int4*)(Vb + ((size_t)krow << 10) + (kt2 + 2) * 64 + kc);
    }
    __syncthreads();
    // odd phase: compute tile kt2+1 from buf1; stage kt2+2 -> buf0;
    // prefetch kt2+3 -> reg set B
    compute_tile(K1, V1);
    if (kt2 + 2 < 16) {
      *(int4*)(&K0[krow * LP + kc]) = kregA;
      *(int2*)(&V0[krow * LP + sbase]) = make_int2(vregA.x, vregA.y);
      *(int2*)(&V0[krow * LP + sbase + 8]) = make_int2(vregA.z, vregA.w);
      kregB = *(const int4*)(Kb + (size_t)((kt2 + 3) * 64 + krow) * 64 + kc);
      vregB = *(const int4*)(Vb + ((size_t)krow << 10) + (kt2 + 3) * 64 + kc);
      __syncthreads();
    }
  }

  // l: reduce across the 4 quads -> full sum per fr; then broadcast to rows.
  l_i += __shfl_xor(l_i, 16, 64);
  l_i += __shfl_xor(l_i, 32, 64);
  float lrow[4];
#pragma unroll
  for (int r = 0; r < 4; ++r) lrow[r] = __shfl(l_i, q4 * 4 + r, 64);

  const int h = bh % 12, bb = bh / 12;
#pragma unroll
  for (int dt = 0; dt < 4; ++dt)
#pragma unroll
    for (int r = 0; r < 4; ++r) {
      int row = bb * 1024 + qt * 128 + wave * 16 + q4 * 4 + r;
      int col = h * 64 + dt * 16 + fr;
      O[(size_t)row * 768 + col] = __float2bfloat16(accO[dt][r] / lrow[r]);
    }
}

// ---------------------------------------------------------------- launch
extern "C" void kernel_launch(void* const* d_in, const int* in_sizes, int n_in,
                              void* d_out, int out_size, void* d_ws, size_t ws_size,
                              hipStream_t stream) {
  const float* x     = (const float*)d_in[0];  // [8192][768]
  const float* Wqkv  = (const float*)d_in[1];  // [768][2304]
  const float* bqkv  = (const float*)d_in[2];  // [2304]
  const float* Wproj = (const float*)d_in[3];  // [768][768]
  const float* bproj = (const float*)d_in[4];  // [768]
  float* out = (float*)d_out;                  // [8192][768] fp32

  constexpr size_t NEEDED = 55050240;
  if (ws_size < NEEDED) {
    ws_diag_kernel<<<(out_size + 255) / 256, 256, 0, stream>>>(
        out, out_size, (float)(ws_size >> 20));
    return;
  }

  char* ws = (char*)d_ws;
  __hip_bfloat16* WqkvT  = (__hip_bfloat16*)(ws);               // 3,538,944 B
  __hip_bfloat16* WprojT = (__hip_bfloat16*)(ws + 3538944);     // 1,179,648 B
  __hip_bfloat16* Qw     = (__hip_bfloat16*)(ws + 4718592);     // 12,582,912 B
  __hip_bfloat16* Kw     = (__hip_bfloat16*)(ws + 17301504);    // 12,582,912 B
  __hip_bfloat16* Vrow   = (__hip_bfloat16*)(ws + 29884416);    // 12,582,912 B
  __hip_bfloat16* xc     = (__hip_bfloat16*)(ws + 42467328);    // 12,582,912 B
  __hip_bfloat16* Vt     = xc;    // xc dead after gemm_qkv
  __hip_bfloat16* attnO  = Vrow;  // Vrow dead after vtrans
  // end = 55,050,240 (proven available)

  prep_kernel<<<5376, 256, 0, stream>>>(x, xc, Wqkv, WqkvT, Wproj, WprojT);
  gemm_qkv_kernel<<<dim3(64, 18), 256, 0, stream>>>(xc, WqkvT, bqkv, Qw, Kw, Vrow);
  vtrans_kernel<<<dim3(96, 16), 256, 0, stream>>>(Vrow, Vt);
  attn_kernel<<<dim3(96 * 8), 512, 0, stream>>>(Qw, Kw, Vt, attnO);
  gemm_proj_kernel<<<dim3(64, 6), 256, 0, stream>>>(attnO, WprojT, bproj, out);
}

// Round 10
// 188.147 us; speedup vs baseline: 1.0517x; 1.0517x over previous
//
#include <hip/hip_runtime.h>
#include <hip/hip_bf16.h>

// MHA forward. Inputs fp32, output fp32, compute bf16 MFMA w/ fp32 accum.
// B=8, N=1024, DIM=768, NH=12, HD=64, M=8192.
// R21: GEMMs/prep/vtrans restored to R17-exact (5/5 GEMM structural
// experiments regressed: R13 swizzle VALU, R16 bounce serialization, R18
// sigma-fuse VGPR, R19 BK=64 VGPR+fetch, R20 dbuf VALU-rematerialization
// 42% -- R11 2-phase @48.2us is a sharp local optimum; GEMM closed).
// NEW (attn): K staged via global_load_lds (T1 DMA) -- linear Ks[64][64],
// inverse-swizzled global source chunk=(tid&7)^(row&7), XOR'd kf reads
// kx0=(q4^(fr&7))*8, kx1=kx0^32 (rule 21: both-sides-or-neither; involution
// verified). Bank-neutral (same 8-cycle b128 floor as LP=72), -8 VGPR
// (kreg pair freed). K gload + V reg-prefetch both issued at PHASE START so
// the compute phase covers their latency even under a conservative
// vmcnt(0)-at-barrier drain. V stays reg-staged (sigma scatter).
// R14 carried (attn): double-buffered K/V reusing dead Q LDS region, 1
// barrier/KV-tile, T14 prefetch, setprio around MFMA (T5).
// R11 carried: 512-thread attn, bare v_exp_f32, S^T operand swap + sigma
// permutation, XCD swizzle bh=bx%96, deferred l-reduction, V pre-transposed.
// WS high-water 55,050,240 B (proven available).

typedef __bf16 bf16x8 __attribute__((ext_vector_type(8)));
typedef float f32x4 __attribute__((ext_vector_type(4)));

#define MFMA16(a, b, c) __builtin_amdgcn_mfma_f32_16x16x32_bf16(a, b, c, 0, 0, 0)

#if defined(__has_builtin) && __has_builtin(__builtin_amdgcn_exp2f)
#define EXP2(x) __builtin_amdgcn_exp2f(x)
#else
#define EXP2(x) exp2f(x)
#endif

__device__ inline __bf16 to_bf16(float f) {
  __hip_bfloat16 h = __float2bfloat16(f);
  return *reinterpret_cast<__bf16*>(&h);
}

// Direct global->LDS DMA, 16B per lane. LDS dest is wave-uniform base + lane*16.
__device__ __forceinline__ void gload16(const void* g, void* l) {
  __builtin_amdgcn_global_load_lds(
      (const __attribute__((address_space(1))) unsigned int*)(unsigned long long)g,
      (__attribute__((address_space(3))) unsigned int*)(unsigned long long)l,
      16, 0, 0);
}

// ---------------------------------------------------------------- diagnostic
__global__ void ws_diag_kernel(float* out, int n, float val) {
  int i = blockIdx.x * 256 + threadIdx.x;
  if (i < n) out[i] = val;
}

// ---------------------------------------------------------------- fused prep
// blocks [0,3072): x fp32 -> xc bf16 (8 elems/thread)
// blocks [3072,4800): Wqkv [768][2304] -> WqkvT [2304][768] bf16 (72x24 tiles)
// blocks [4800,5376): Wproj [768][768] -> WprojT [768][768] bf16 (24x24 tiles)
__global__ __launch_bounds__(256) void prep_kernel(
    const float* __restrict__ x, __hip_bfloat16* __restrict__ xc,
    const float* __restrict__ Wqkv, __hip_bfloat16* __restrict__ WqkvT,
    const float* __restrict__ Wproj, __hip_bfloat16* __restrict__ WprojT) {
  __shared__ __hip_bfloat16 tile[32][33];
  const int b = blockIdx.x;
  if (b < 3072) {
    int i = b * 256 + threadIdx.x;
    float4 a = ((const float4*)x)[i * 2], c = ((const float4*)x)[i * 2 + 1];
    __hip_bfloat16 o[8] = {__float2bfloat16(a.x), __float2bfloat16(a.y),
                           __float2bfloat16(a.z), __float2bfloat16(a.w),
                           __float2bfloat16(c.x), __float2bfloat16(c.y),
                           __float2bfloat16(c.z), __float2bfloat16(c.w)};
    *(int4*)(xc + (size_t)i * 8) = *(const int4*)o;
    return;
  }
  const float* W;
  __hip_bfloat16* Wt;
  int rows, cols, bx, by;
  if (b < 4800) {
    int idx = b - 3072;  // 72 x 24 tile grid
    W = Wqkv; Wt = WqkvT; rows = 768; cols = 2304;
    bx = idx % 72; by = idx / 72;
  } else {
    int idx = b - 4800;  // 24 x 24 tile grid
    W = Wproj; Wt = WprojT; rows = 768; cols = 768;
    bx = idx % 24; by = idx / 24;
  }
  const int tc = bx * 32, tr = by * 32;
  const int tx = threadIdx.x & 31, ty = threadIdx.x >> 5;  // (32,8)
#pragma unroll
  for (int i = 0; i < 4; ++i) {
    int r = ty + i * 8;
    tile[r][tx] = __float2bfloat16(W[(size_t)(tr + r) * cols + tc + tx]);
  }
  __syncthreads();
#pragma unroll
  for (int i = 0; i < 4; ++i) {
    int r = ty + i * 8;
    Wt[(size_t)(tc + r) * rows + tr + tx] = tile[tx][r];
  }
}

// ---------------------------------------------------------------- V transpose
// Vrow [96][1024][64] -> Vt [96][64][1024]. 64x64 bf16 tile per block.
__global__ __launch_bounds__(256) void vtrans_kernel(
    const __hip_bfloat16* __restrict__ Vrow, __hip_bfloat16* __restrict__ Vt) {
  constexpr int LP = 72;
  __shared__ __bf16 tile[64 * LP];
  const int tid = threadIdx.x;
  const int bh = blockIdx.x;
  const int n0 = blockIdx.y * 64;
  const size_t base = (size_t)bh << 16;
#pragma unroll
  for (int i = 0; i < 2; ++i) {
    int s = tid + 256 * i;
    int r = s >> 3, c8 = (s & 7) * 8;
    *(int4*)(&tile[r * LP + c8]) =
        *(const int4*)(Vrow + base + (size_t)(n0 + r) * 64 + c8);
  }
  __syncthreads();
#pragma unroll
  for (int i = 0; i < 2; ++i) {
    int s = tid + 256 * i;
    int d = s >> 3, n8 = (s & 7) * 8;
    __bf16 o[8];
#pragma unroll
    for (int j = 0; j < 8; ++j) o[j] = tile[(n8 + j) * LP + d];
    *(int4*)(Vt + base + ((size_t)d << 10) + n0 + n8) = *(const int4*)o;
  }
}

// ---------------------------------------------------------------- GEMM common
constexpr int GK = 768;

// ---------------------------------------------------------------- QKV GEMM
// R11-exact: 128x128 tile, BK=32 (24 K-steps), 4 waves, 16KB LDS, VGPR 80.
__global__ __launch_bounds__(256) void gemm_qkv_kernel(
    const __hip_bfloat16* __restrict__ A,    // xc bf16 [8192][768]
    const __hip_bfloat16* __restrict__ Bt,   // WqkvT [2304][768] bf16
    const float* __restrict__ bias,          // b_qkv fp32 [2304]
    __hip_bfloat16* __restrict__ Qw,         // [96][1024][64] (Q scaled log2e/8)
    __hip_bfloat16* __restrict__ Kw,         // [96][1024][64]
    __hip_bfloat16* __restrict__ Vw) {       // [96][1024][64] row-major
  __shared__ __align__(16) __bf16 As[128 * 32];
  __shared__ __align__(16) __bf16 Bs[128 * 32];
  const int tid = threadIdx.x;
  const int lane = tid & 63, wave = tid >> 6;
  const int wr = wave >> 1, wc = wave & 1;
  const int m0 = blockIdx.x * 128, n0 = blockIdx.y * 128;
  const int fr = lane & 15, q4 = lane >> 4;

  const int r4 = lane >> 2, c8 = (lane & 3) * 8;
  const __hip_bfloat16* ga0 = A + (size_t)(m0 + wave * 32 + r4) * GK + c8;
  const __hip_bfloat16* gb0 = Bt + (size_t)(n0 + wave * 32 + r4) * GK + c8;
  __bf16* la0 = &As[wave * 1024];
  __bf16* lb0 = &Bs[wave * 1024];

  f32x4 acc[4][4] = {};

  for (int kt = 0; kt < GK / 32; ++kt) {
    __syncthreads();
    gload16(ga0 + kt * 32, la0);
    gload16(ga0 + kt * 32 + 16 * GK, la0 + 512);
    gload16(gb0 + kt * 32, lb0);
    gload16(gb0 + kt * 32 + 16 * GK, lb0 + 512);
    __syncthreads();
    bf16x8 af[4], bfr[4];
#pragma unroll
    for (int i = 0; i < 4; ++i)
      af[i] = *(const bf16x8*)(&As[(wr * 64 + i * 16 + fr) * 32 + q4 * 8]);
#pragma unroll
    for (int j = 0; j < 4; ++j)
      bfr[j] = *(const bf16x8*)(&Bs[(wc * 64 + j * 16 + fr) * 32 + q4 * 8]);
#pragma unroll
    for (int i = 0; i < 4; ++i)
#pragma unroll
      for (int j = 0; j < 4; ++j)
        acc[i][j] = MFMA16(af[i], bfr[j], acc[i][j]);
  }

#pragma unroll
  for (int j = 0; j < 4; ++j) {
    int col = n0 + wc * 64 + j * 16 + fr;
    int which = col / 768;
    int rem = col - which * 768;
    int h = rem >> 6, d = rem & 63;
    float bv = bias[col];
    __hip_bfloat16* dst = (which == 0) ? Qw : (which == 1) ? Kw : Vw;
    // Q scale = 1/sqrt(64) * log2(e), so attention can use raw exp2.
    float scale = (which == 0) ? 0.18033688011112042f : 1.0f;
#pragma unroll
    for (int i = 0; i < 4; ++i) {
#pragma unroll
      for (int r = 0; r < 4; ++r) {
        int row = m0 + wr * 64 + i * 16 + q4 * 4 + r;
        int bb = row >> 10, nn = row & 1023;
        float v = (acc[i][j][r] + bv) * scale;
        dst[(((size_t)(bb * 12 + h) * 1024 + nn) << 6) + d] = __float2bfloat16(v);
      }
    }
  }
}

// ---------------------------------------------------------------- proj GEMM
__global__ __launch_bounds__(256) void gemm_proj_kernel(
    const __hip_bfloat16* __restrict__ A,   // attnO bf16 [8192][768]
    const __hip_bfloat16* __restrict__ Bt,  // WprojT bf16 [768][768]
    const float* __restrict__ bias,         // b_proj fp32 [768]
    float* __restrict__ out) {              // d_out fp32 [8192][768]
  __shared__ __align__(16) __bf16 As[128 * 32];
  __shared__ __align__(16) __bf16 Bs[128 * 32];
  const int tid = threadIdx.x;
  const int lane = tid & 63, wave = tid >> 6;
  const int wr = wave >> 1, wc = wave & 1;
  const int m0 = blockIdx.x * 128, n0 = blockIdx.y * 128;
  const int fr = lane & 15, q4 = lane >> 4;

  const int r4 = lane >> 2, c8 = (lane & 3) * 8;
  const __hip_bfloat16* ga0 = A + (size_t)(m0 + wave * 32 + r4) * GK + c8;
  const __hip_bfloat16* gb0 = Bt + (size_t)(n0 + wave * 32 + r4) * GK + c8;
  __bf16* la0 = &As[wave * 1024];
  __bf16* lb0 = &Bs[wave * 1024];

  f32x4 acc[4][4] = {};

  for (int kt = 0; kt < GK / 32; ++kt) {
    __syncthreads();
    gload16(ga0 + kt * 32, la0);
    gload16(ga0 + kt * 32 + 16 * GK, la0 + 512);
    gload16(gb0 + kt * 32, lb0);
    gload16(gb0 + kt * 32 + 16 * GK, lb0 + 512);
    __syncthreads();
    bf16x8 af[4], bfr[4];
#pragma unroll
    for (int i = 0; i < 4; ++i)
      af[i] = *(const bf16x8*)(&As[(wr * 64 + i * 16 + fr) * 32 + q4 * 8]);
#pragma unroll
    for (int j = 0; j < 4; ++j)
      bfr[j] = *(const bf16x8*)(&Bs[(wc * 64 + j * 16 + fr) * 32 + q4 * 8]);
#pragma unroll
    for (int i = 0; i < 4; ++i)
#pragma unroll
      for (int j = 0; j < 4; ++j)
        acc[i][j] = MFMA16(af[i], bfr[j], acc[i][j]);
  }

#pragma unroll
  for (int j = 0; j < 4; ++j) {
    int col = n0 + wc * 64 + j * 16 + fr;
    float bv = bias[col];
#pragma unroll
    for (int i = 0; i < 4; ++i) {
#pragma unroll
      for (int r = 0; r < 4; ++r) {
        int row = m0 + wr * 64 + i * 16 + q4 * 4 + r;
        out[(size_t)row * 768 + col] = acc[i][j][r] + bv;
      }
    }
  }
}

// ---------------------------------------------------------------- attention
// block = (b,h,128 q-rows); 8 waves x 16 qrows; KV tiles of 64 keys.
// S^T = K.Q^T via operand swap; P stays in registers (sigma key permutation
// shared by P regs and V LDS layout). XCD swizzle bh=bx%96.
// K staged via global_load_lds into LINEAR Ks[64][64] (8KB/buf): global
// source pre-swizzled chunk=(tid&7)^(row&7), kf reads XOR'd kx0/kx1.
// V reg-staged with sigma scatter (unchanged). Double-buffered; buf1 reuses
// dead Q region. K gload + V prefetch issued at PHASE START (latency covered
// by compute even if barrier drains vmcnt(0)). One barrier per KV tile.
__global__ __launch_bounds__(512) void attn_kernel(
    const __hip_bfloat16* __restrict__ Qw,  // [96][1024][64], scaled log2e/8
    const __hip_bfloat16* __restrict__ Kw,  // [96][1024][64]
    const __hip_bfloat16* __restrict__ Vt,  // [96][64][1024]
    __hip_bfloat16* __restrict__ O) {       // attnO [8192][768], col = h*64+d
  constexpr int LP = 72;
  // [0,9216): Q staging, then buf1 {K1@0 (4096, linear), V1@4608 (LP=72)}
  // [9216,18432): buf0 {K0@9216 (4096, linear), V0@13824 (LP=72)}
  __shared__ __align__(16) __bf16 smem[18432];
  __bf16* Qs = smem;
  __bf16* K1 = smem;
  __bf16* V1 = smem + 4608;
  __bf16* K0 = smem + 9216;
  __bf16* V0 = smem + 13824;
  const int tid = threadIdx.x;
  const int lane = tid & 63, wave = tid >> 6;  // 8 waves
  const int fr = lane & 15, q4 = lane >> 4;
  const int bh = blockIdx.x % 96, qt = blockIdx.x / 96;  // XCD-local KV
  const __hip_bfloat16* Qb = Qw + ((size_t)bh * 1024 + qt * 128) * 64;
  const __hip_bfloat16* Kb = Kw + (size_t)bh * 65536;
  const __hip_bfloat16* Vb = Vt + (size_t)bh * 65536;

  // K staging addresses: row tid>>3, pre-swizzled chunk (tid&7)^(row&7).
  const int krow = tid >> 3;
  const int kchunk = ((tid & 7) ^ (krow & 7)) * 8;  // elems
  const __hip_bfloat16* ksrc = Kb + (size_t)krow * 64 + kchunk;  // + kt*4096
  __bf16* kdst0 = K0 + wave * 512;  // wave-uniform dest base (512 elems=1KB)
  __bf16* kdst1 = K1 + wave * 512;
  // V staging (reg->LDS sigma scatter, unchanged from R14)
  const int kc = (tid & 7) * 8;
  const int sc8 = tid & 7;
  const int sbase = ((sc8 >> 2) << 5) | ((sc8 & 1) << 4) | (((sc8 >> 1) & 1) << 2);
  // kf read offsets (XOR undo of source swizzle; x1 = x0 ^ 4 chunks)
  const int kx0 = (q4 ^ (fr & 7)) * 8;
  const int kx1 = kx0 ^ 32;

  // prolog: K(0) gload early (covered by Q staging); V(0) prefetch
  gload16(ksrc, kdst0);
  int4 vregA = *(const int4*)(Vb + ((size_t)krow << 10) + kc);

  // stage Q 128x64 (2 int4/thread)
#pragma unroll
  for (int i = 0; i < 2; ++i) {
    int s = tid + 512 * i;
    int row = s >> 3, c = (s & 7) * 8;
    *(int4*)(&Qs[row * LP + c]) = *(const int4*)(Qb + row * 64 + c);
  }
  __syncthreads();  // Q staged; K0 gload drained
  bf16x8 qf[2];
#pragma unroll
  for (int ks = 0; ks < 2; ++ks)
    qf[ks] = *(const bf16x8*)(&Qs[(wave * 16 + fr) * LP + ks * 32 + q4 * 8]);

  float l_i = 0.f;        // per-lane partial over this lane's 16 keys/iter
  f32x4 accO[4] = {};     // C-layout: row=qrow(q4*4+r), col=d(dt*16+fr)

  // finish buf0: V(0) to LDS; prefetch V(1)
  *(int2*)(&V0[krow * LP + sbase]) = make_int2(vregA.x, vregA.y);
  *(int2*)(&V0[krow * LP + sbase + 8]) = make_int2(vregA.z, vregA.w);
  int4 vregB = *(const int4*)(Vb + ((size_t)krow << 10) + 64 + kc);
  __syncthreads();  // buf0 ready; qf reads done -> Q region (K1,V1) free

  auto compute_tile = [&](const __bf16* Kbuf, const __bf16* Vbuf) {
    // S^T = K.Q^T: scT[nt][r] = P[qrow=wave*16+fr][key=nt*16+q4*4+r]
    f32x4 scT[4];
    __builtin_amdgcn_s_setprio(1);
#pragma unroll
    for (int nt = 0; nt < 4; ++nt) {
      bf16x8 kf0 = *(const bf16x8*)(&Kbuf[(nt * 16 + fr) * 64 + kx0]);
      bf16x8 kf1 = *(const bf16x8*)(&Kbuf[(nt * 16 + fr) * 64 + kx1]);
      f32x4 z = {};
      z = MFMA16(kf0, qf[0], z);
      scT[nt] = MFMA16(kf1, qf[1], z);
    }
    __builtin_amdgcn_s_setprio(0);
    // p = 2^s (bare v_exp_f32); per-lane l partial
    float rs = 0.f;
#pragma unroll
    for (int nt = 0; nt < 4; ++nt)
#pragma unroll
      for (int r = 0; r < 4; ++r) {
        float p = EXP2(scT[nt][r]);
        scT[nt][r] = p;
        rs += p;
      }
    l_i += rs;
    // O += P.V — P A-fragments are this lane's own registers under sigma
#pragma unroll
    for (int ks = 0; ks < 2; ++ks) {
      bf16x8 pf;
#pragma unroll
      for (int e = 0; e < 4; ++e) {
        pf[e] = to_bf16(scT[2 * ks][e]);
        pf[4 + e] = to_bf16(scT[2 * ks + 1][e]);
      }
      __builtin_amdgcn_s_setprio(1);
#pragma unroll
      for (int dt = 0; dt < 4; ++dt) {
        bf16x8 vf = *(const bf16x8*)(&Vbuf[(dt * 16 + fr) * LP + ks * 32 + q4 * 8]);
        accO[dt] = MFMA16(pf, vf, accO[dt]);
      }
      __builtin_amdgcn_s_setprio(0);
    }
  };

  for (int kt2 = 0; kt2 < 16; kt2 += 2) {
    // even phase: compute tile kt2 from buf0; stage kt2+1 -> buf1.
    // Issue loads FIRST (covered by compute): K(kt2+1) gload -> K1,
    // V(kt2+2) prefetch -> vregA.
    gload16(ksrc + (size_t)(kt2 + 1) * 4096, kdst1);
    if (kt2 + 2 < 16)
      vregA = *(const int4*)(Vb + ((size_t)krow << 10) + (kt2 + 2) * 64 + kc);
    compute_tile(K0, V0);
    *(int2*)(&V1[krow * LP + sbase]) = make_int2(vregB.x, vregB.y);
    *(int2*)(&V1[krow * LP + sbase + 8]) = make_int2(vregB.z, vregB.w);
    __syncthreads();
    // odd phase: compute tile kt2+1 from buf1; stage kt2+2 -> buf0.
    if (kt2 + 2 < 16) {
      gload16(ksrc + (size_t)(kt2 + 2) * 4096, kdst0);
      if (kt2 + 3 < 16)
        vregB = *(const int4*)(Vb + ((size_t)krow << 10) + (kt2 + 3) * 64 + kc);
      compute_tile(K1, V1);
      *(int2*)(&V0[krow * LP + sbase]) = make_int2(vregA.x, vregA.y);
      *(int2*)(&V0[krow * LP + sbase + 8]) = make_int2(vregA.z, vregA.w);
      __syncthreads();
    } else {
      compute_tile(K1, V1);
    }
  }

  // l: reduce across the 4 quads -> full sum per fr; then broadcast to rows.
  l_i += __shfl_xor(l_i, 16, 64);
  l_i += __shfl_xor(l_i, 32, 64);
  float lrow[4];
#pragma unroll
  for (int r = 0; r < 4; ++r) lrow[r] = __shfl(l_i, q4 * 4 + r, 64);

  const int h = bh % 12, bb = bh / 12;
#pragma unroll
  for (int dt = 0; dt < 4; ++dt)
#pragma unroll
    for (int r = 0; r < 4; ++r) {
      int row = bb * 1024 + qt * 128 + wave * 16 + q4 * 4 + r;
      int col = h * 64 + dt * 16 + fr;
      O[(size_t)row * 768 + col] = __float2bfloat16(accO[dt][r] / lrow[r]);
    }
}

// ---------------------------------------------------------------- launch
extern "C" void kernel_launch(void* const* d_in, const int* in_sizes, int n_in,
                              void* d_out, int out_size, void* d_ws, size_t ws_size,
                              hipStream_t stream) {
  const float* x     = (const float*)d_in[0];  // [8192][768]
  const float* Wqkv  = (const float*)d_in[1];  // [768][2304]
  const float* bqkv  = (const float*)d_in[2];  // [2304]
  const float* Wproj = (const float*)d_in[3];  // [768][768]
  const float* bproj = (const float*)d_in[4];  // [768]
  float* out = (float*)d_out;                  // [8192][768] fp32

  constexpr size_t NEEDED = 55050240;
  if (ws_size < NEEDED) {
    ws_diag_kernel<<<(out_size + 255) / 256, 256, 0, stream>>>(
        out, out_size, (float)(ws_size >> 20));
    return;
  }

  char* ws = (char*)d_ws;
  __hip_bfloat16* WqkvT  = (__hip_bfloat16*)(ws);               // 3,538,944 B
  __hip_bfloat16* WprojT = (__hip_bfloat16*)(ws + 3538944);     // 1,179,648 B
  __hip_bfloat16* Qw     = (__hip_bfloat16*)(ws + 4718592);     // 12,582,912 B
  __hip_bfloat16* Kw     = (__hip_bfloat16*)(ws + 17301504);    // 12,582,912 B
  __hip_bfloat16* Vrow   = (__hip_bfloat16*)(ws + 29884416);    // 12,582,912 B
  __hip_bfloat16* xc     = (__hip_bfloat16*)(ws + 42467328);    // 12,582,912 B
  __hip_bfloat16* Vt     = xc;    // xc dead after gemm_qkv
  __hip_bfloat16* attnO  = Vrow;  // Vrow dead after vtrans
  // end = 55,050,240 (proven available)

  prep_kernel<<<5376, 256, 0, stream>>>(x, xc, Wqkv, WqkvT, Wproj, WprojT);
  gemm_qkv_kernel<<<dim3(64, 18), 256, 0, stream>>>(xc, WqkvT, bqkv, Qw, Kw, Vrow);
  vtrans_kernel<<<dim3(96, 16), 256, 0, stream>>>(Vrow, Vt);
  attn_kernel<<<dim3(96 * 8), 512, 0, stream>>>(Qw, Kw, Vt, attnO);
  gemm_proj_kernel<<<dim3(64, 6), 256, 0, stream>>>(attnO, WprojT, bproj, out);
}

// Round 11
// 186.369 us; speedup vs baseline: 1.0617x; 1.0095x over previous
//
#include <hip/hip_runtime.h>
#include <hip/hip_bf16.h>

// MHA forward. Inputs fp32, output fp32, compute bf16 MFMA w/ fp32 accum.
// B=8, N=1024, DIM=768, NH=12, HD=64, M=8192.
// R22: V joins K on the gload path. vtrans now emits Vsig [96][16kt][64d][64]
// with sigma AND bank-XOR pre-baked: position p=sigma(key) stored at in-row
// addr ((p>>3)^(d&7))*8+(p&7) (pieces are int2, 8B-aligned, same 128B row ->
// full-line write combining, NOT the R14 scatter trap). attn stages V with a
// single linear gload16 (vsrc = Vsig + tid*8) and reads vf at the SAME
// XOR'd offsets as K (sx0=(q4^(fr&7))*8, sx1=sx0^32) since row&7=fr&7 for
// both. Removes per tile: V int4 load + 2 int2 ds_writes + sigma VALU.
// LDS 36.9->34.8KB. Prolog: second barrier so all waves' qf reads complete
// before first DMA into the Q-region buffer (R21 discipline).
// R21 carried: K via gload w/ pre-swizzled source + XOR reads (rule 21,
// proven +3us); GEMMs R11-exact (5/5 structural experiments regressed --
// qkv 48.2us is a sharp local optimum, GEMM closed); fused prep.
// R11/R14 carried: 512-thread attn, dbuf 1-barrier/KV-tile, setprio (T5),
// bare v_exp_f32, S^T operand swap, XCD swizzle bh=bx%96, deferred l.
// WS high-water 55,050,240 B (proven available).

typedef __bf16 bf16x8 __attribute__((ext_vector_type(8)));
typedef float f32x4 __attribute__((ext_vector_type(4)));

#define MFMA16(a, b, c) __builtin_amdgcn_mfma_f32_16x16x32_bf16(a, b, c, 0, 0, 0)

#if defined(__has_builtin) && __has_builtin(__builtin_amdgcn_exp2f)
#define EXP2(x) __builtin_amdgcn_exp2f(x)
#else
#define EXP2(x) exp2f(x)
#endif

__device__ inline __bf16 to_bf16(float f) {
  __hip_bfloat16 h = __float2bfloat16(f);
  return *reinterpret_cast<__bf16*>(&h);
}

// Direct global->LDS DMA, 16B per lane. LDS dest is wave-uniform base + lane*16.
__device__ __forceinline__ void gload16(const void* g, void* l) {
  __builtin_amdgcn_global_load_lds(
      (const __attribute__((address_space(1))) unsigned int*)(unsigned long long)g,
      (__attribute__((address_space(3))) unsigned int*)(unsigned long long)l,
      16, 0, 0);
}

// ---------------------------------------------------------------- diagnostic
__global__ void ws_diag_kernel(float* out, int n, float val) {
  int i = blockIdx.x * 256 + threadIdx.x;
  if (i < n) out[i] = val;
}

// ---------------------------------------------------------------- fused prep
// blocks [0,3072): x fp32 -> xc bf16 (8 elems/thread)
// blocks [3072,4800): Wqkv [768][2304] -> WqkvT [2304][768] bf16 (72x24 tiles)
// blocks [4800,5376): Wproj [768][768] -> WprojT [768][768] bf16 (24x24 tiles)
__global__ __launch_bounds__(256) void prep_kernel(
    const float* __restrict__ x, __hip_bfloat16* __restrict__ xc,
    const float* __restrict__ Wqkv, __hip_bfloat16* __restrict__ WqkvT,
    const float* __restrict__ Wproj, __hip_bfloat16* __restrict__ WprojT) {
  __shared__ __hip_bfloat16 tile[32][33];
  const int b = blockIdx.x;
  if (b < 3072) {
    int i = b * 256 + threadIdx.x;
    float4 a = ((const float4*)x)[i * 2], c = ((const float4*)x)[i * 2 + 1];
    __hip_bfloat16 o[8] = {__float2bfloat16(a.x), __float2bfloat16(a.y),
                           __float2bfloat16(a.z), __float2bfloat16(a.w),
                           __float2bfloat16(c.x), __float2bfloat16(c.y),
                           __float2bfloat16(c.z), __float2bfloat16(c.w)};
    *(int4*)(xc + (size_t)i * 8) = *(const int4*)o;
    return;
  }
  const float* W;
  __hip_bfloat16* Wt;
  int rows, cols, bx, by;
  if (b < 4800) {
    int idx = b - 3072;  // 72 x 24 tile grid
    W = Wqkv; Wt = WqkvT; rows = 768; cols = 2304;
    bx = idx % 72; by = idx / 72;
  } else {
    int idx = b - 4800;  // 24 x 24 tile grid
    W = Wproj; Wt = WprojT; rows = 768; cols = 768;
    bx = idx % 24; by = idx / 24;
  }
  const int tc = bx * 32, tr = by * 32;
  const int tx = threadIdx.x & 31, ty = threadIdx.x >> 5;  // (32,8)
#pragma unroll
  for (int i = 0; i < 4; ++i) {
    int r = ty + i * 8;
    tile[r][tx] = __float2bfloat16(W[(size_t)(tr + r) * cols + tc + tx]);
  }
  __syncthreads();
#pragma unroll
  for (int i = 0; i < 4; ++i) {
    int r = ty + i * 8;
    Wt[(size_t)(tc + r) * rows + tr + tx] = tile[tx][r];
  }
}

// ---------------------------------------------------------------- V transpose
// Vrow [96][1024][64] -> Vsig [96][16 kt][64 d][64]: position p=sigma(key)
// at in-row addr ((p>>3)^(d&7))*8 + (p&7). sigma_base(c) =
// ((c>>2)<<5)|((c&1)<<4)|(((c>>1)&1)<<2); pos(key)=sb(key>>3)+((key>>2)&1)*8
// +(key&3). Pieces int2 (8B-aligned), all within one 128B row.
__global__ __launch_bounds__(256) void vtrans_kernel(
    const __hip_bfloat16* __restrict__ Vrow, __hip_bfloat16* __restrict__ Vsig) {
  constexpr int LP = 72;
  __shared__ __bf16 tile[64 * LP];
  const int tid = threadIdx.x;
  const int bh = blockIdx.x;
  const int n0 = blockIdx.y * 64;  // kt = blockIdx.y
  const size_t base = (size_t)bh << 16;
#pragma unroll
  for (int i = 0; i < 2; ++i) {
    int s = tid + 256 * i;
    int r = s >> 3, c8 = (s & 7) * 8;
    *(int4*)(&tile[r * LP + c8]) =
        *(const int4*)(Vrow + base + (size_t)(n0 + r) * 64 + c8);
  }
  __syncthreads();
#pragma unroll
  for (int i = 0; i < 2; ++i) {
    int s = tid + 256 * i;
    int d = s >> 3, c = s & 7;
    int n8 = c * 8;
    __bf16 o[8];
#pragma unroll
    for (int j = 0; j < 8; ++j) o[j] = tile[(n8 + j) * LP + d];
    int sb = ((c >> 2) << 5) | ((c & 1) << 4) | (((c >> 1) & 1) << 2);
    int x = d & 7;
    int a0 = (((sb >> 3) ^ x) << 3) | (sb & 7);
    int a1 = ((((sb >> 3) + 1) ^ x) << 3) | (sb & 7);
    __hip_bfloat16* vr = Vsig + base + (size_t)blockIdx.y * 4096 + d * 64;
    *(int2*)(vr + a0) = *(const int2*)&o[0];
    *(int2*)(vr + a1) = *(const int2*)&o[4];
  }
}

// ---------------------------------------------------------------- GEMM common
constexpr int GK = 768;

// ---------------------------------------------------------------- QKV GEMM
// R11-exact: 128x128 tile, BK=32 (24 K-steps), 4 waves, 16KB LDS, VGPR 80.
__global__ __launch_bounds__(256) void gemm_qkv_kernel(
    const __hip_bfloat16* __restrict__ A,    // xc bf16 [8192][768]
    const __hip_bfloat16* __restrict__ Bt,   // WqkvT [2304][768] bf16
    const float* __restrict__ bias,          // b_qkv fp32 [2304]
    __hip_bfloat16* __restrict__ Qw,         // [96][1024][64] (Q scaled log2e/8)
    __hip_bfloat16* __restrict__ Kw,         // [96][1024][64]
    __hip_bfloat16* __restrict__ Vw) {       // [96][1024][64] row-major
  __shared__ __align__(16) __bf16 As[128 * 32];
  __shared__ __align__(16) __bf16 Bs[128 * 32];
  const int tid = threadIdx.x;
  const int lane = tid & 63, wave = tid >> 6;
  const int wr = wave >> 1, wc = wave & 1;
  const int m0 = blockIdx.x * 128, n0 = blockIdx.y * 128;
  const int fr = lane & 15, q4 = lane >> 4;

  const int r4 = lane >> 2, c8 = (lane & 3) * 8;
  const __hip_bfloat16* ga0 = A + (size_t)(m0 + wave * 32 + r4) * GK + c8;
  const __hip_bfloat16* gb0 = Bt + (size_t)(n0 + wave * 32 + r4) * GK + c8;
  __bf16* la0 = &As[wave * 1024];
  __bf16* lb0 = &Bs[wave * 1024];

  f32x4 acc[4][4] = {};

  for (int kt = 0; kt < GK / 32; ++kt) {
    __syncthreads();
    gload16(ga0 + kt * 32, la0);
    gload16(ga0 + kt * 32 + 16 * GK, la0 + 512);
    gload16(gb0 + kt * 32, lb0);
    gload16(gb0 + kt * 32 + 16 * GK, lb0 + 512);
    __syncthreads();
    bf16x8 af[4], bfr[4];
#pragma unroll
    for (int i = 0; i < 4; ++i)
      af[i] = *(const bf16x8*)(&As[(wr * 64 + i * 16 + fr) * 32 + q4 * 8]);
#pragma unroll
    for (int j = 0; j < 4; ++j)
      bfr[j] = *(const bf16x8*)(&Bs[(wc * 64 + j * 16 + fr) * 32 + q4 * 8]);
#pragma unroll
    for (int i = 0; i < 4; ++i)
#pragma unroll
      for (int j = 0; j < 4; ++j)
        acc[i][j] = MFMA16(af[i], bfr[j], acc[i][j]);
  }

#pragma unroll
  for (int j = 0; j < 4; ++j) {
    int col = n0 + wc * 64 + j * 16 + fr;
    int which = col / 768;
    int rem = col - which * 768;
    int h = rem >> 6, d = rem & 63;
    float bv = bias[col];
    __hip_bfloat16* dst = (which == 0) ? Qw : (which == 1) ? Kw : Vw;
    // Q scale = 1/sqrt(64) * log2(e), so attention can use raw exp2.
    float scale = (which == 0) ? 0.18033688011112042f : 1.0f;
#pragma unroll
    for (int i = 0; i < 4; ++i) {
#pragma unroll
      for (int r = 0; r < 4; ++r) {
        int row = m0 + wr * 64 + i * 16 + q4 * 4 + r;
        int bb = row >> 10, nn = row & 1023;
        float v = (acc[i][j][r] + bv) * scale;
        dst[(((size_t)(bb * 12 + h) * 1024 + nn) << 6) + d] = __float2bfloat16(v);
      }
    }
  }
}

// ---------------------------------------------------------------- proj GEMM
__global__ __launch_bounds__(256) void gemm_proj_kernel(
    const __hip_bfloat16* __restrict__ A,   // attnO bf16 [8192][768]
    const __hip_bfloat16* __restrict__ Bt,  // WprojT bf16 [768][768]
    const float* __restrict__ bias,         // b_proj fp32 [768]
    float* __restrict__ out) {              // d_out fp32 [8192][768]
  __shared__ __align__(16) __bf16 As[128 * 32];
  __shared__ __align__(16) __bf16 Bs[128 * 32];
  const int tid = threadIdx.x;
  const int lane = tid & 63, wave = tid >> 6;
  const int wr = wave >> 1, wc = wave & 1;
  const int m0 = blockIdx.x * 128, n0 = blockIdx.y * 128;
  const int fr = lane & 15, q4 = lane >> 4;

  const int r4 = lane >> 2, c8 = (lane & 3) * 8;
  const __hip_bfloat16* ga0 = A + (size_t)(m0 + wave * 32 + r4) * GK + c8;
  const __hip_bfloat16* gb0 = Bt + (size_t)(n0 + wave * 32 + r4) * GK + c8;
  __bf16* la0 = &As[wave * 1024];
  __bf16* lb0 = &Bs[wave * 1024];

  f32x4 acc[4][4] = {};

  for (int kt = 0; kt < GK / 32; ++kt) {
    __syncthreads();
    gload16(ga0 + kt * 32, la0);
    gload16(ga0 + kt * 32 + 16 * GK, la0 + 512);
    gload16(gb0 + kt * 32, lb0);
    gload16(gb0 + kt * 32 + 16 * GK, lb0 + 512);
    __syncthreads();
    bf16x8 af[4], bfr[4];
#pragma unroll
    for (int i = 0; i < 4; ++i)
      af[i] = *(const bf16x8*)(&As[(wr * 64 + i * 16 + fr) * 32 + q4 * 8]);
#pragma unroll
    for (int j = 0; j < 4; ++j)
      bfr[j] = *(const bf16x8*)(&Bs[(wc * 64 + j * 16 + fr) * 32 + q4 * 8]);
#pragma unroll
    for (int i = 0; i < 4; ++i)
#pragma unroll
      for (int j = 0; j < 4; ++j)
        acc[i][j] = MFMA16(af[i], bfr[j], acc[i][j]);
  }

#pragma unroll
  for (int j = 0; j < 4; ++j) {
    int col = n0 + wc * 64 + j * 16 + fr;
    float bv = bias[col];
#pragma unroll
    for (int i = 0; i < 4; ++i) {
#pragma unroll
      for (int r = 0; r < 4; ++r) {
        int row = m0 + wr * 64 + i * 16 + q4 * 4 + r;
        out[(size_t)row * 768 + col] = acc[i][j][r] + bv;
      }
    }
  }
}

// ---------------------------------------------------------------- attention
// block = (b,h,128 q-rows); 8 waves x 16 qrows; KV tiles of 64 keys.
// S^T = K.Q^T via operand swap; P stays in registers (sigma pre-baked in
// Vsig). K AND V staged via global_load_lds into linear 4KB-elem buffers;
// both read at XOR'd offsets sx0/sx1 (K: source pre-swizzled at staging;
// V: swizzle pre-baked in Vsig by vtrans). One barrier per KV tile; DMA
// for tile t+1 issued before compute(t) (latency covered by compute).
__global__ __launch_bounds__(512) void attn_kernel(
    const __hip_bfloat16* __restrict__ Qw,  // [96][1024][64], scaled log2e/8
    const __hip_bfloat16* __restrict__ Kw,  // [96][1024][64]
    const __hip_bfloat16* __restrict__ Vsig,// [96][16][64][64] sigma+swz
    __hip_bfloat16* __restrict__ O) {       // attnO [8192][768], col = h*64+d
  constexpr int LP = 72;
  // [0,8192): buf1 {K1@0, V1@4096}; Qs@0 (9216, overlaps buf1, dead after qf)
  // [9216,17408): buf0 {K0@9216, V0@13312}
  __shared__ __align__(16) __bf16 smem[17408];
  __bf16* Qs = smem;
  __bf16* K1 = smem;
  __bf16* V1 = smem + 4096;
  __bf16* K0 = smem + 9216;
  __bf16* V0 = smem + 13312;
  const int tid = threadIdx.x;
  const int lane = tid & 63, wave = tid >> 6;  // 8 waves
  const int fr = lane & 15, q4 = lane >> 4;
  const int bh = blockIdx.x % 96, qt = blockIdx.x / 96;  // XCD-local KV
  const __hip_bfloat16* Qb = Qw + ((size_t)bh * 1024 + qt * 128) * 64;
  const __hip_bfloat16* Kb = Kw + (size_t)bh * 65536;
  const __hip_bfloat16* Vb = Vsig + (size_t)bh * 65536;

  // staging addresses: K source pre-swizzled; V source linear (pre-baked).
  const int krow = tid >> 3;
  const int kchunk = ((tid & 7) ^ (krow & 7)) * 8;
  const __hip_bfloat16* ksrc = Kb + (size_t)krow * 64 + kchunk;  // + kt*4096
  const __hip_bfloat16* vsrc = Vb + (size_t)tid * 8;             // + kt*4096
  __bf16* kd0 = K0 + wave * 512;
  __bf16* kd1 = K1 + wave * 512;
  __bf16* vd0 = V0 + wave * 512;
  __bf16* vd1 = V1 + wave * 512;
  // XOR'd fragment-read offsets (shared by K and V: row&7 == fr&7)
  const int sx0 = (q4 ^ (fr & 7)) * 8;
  const int sx1 = sx0 ^ 32;

  // prolog: DMA tile 0 -> buf0 (covered by Q staging)
  gload16(ksrc, kd0);
  gload16(vsrc, vd0);

  // stage Q 128x64 (2 int4/thread)
#pragma unroll
  for (int i = 0; i < 2; ++i) {
    int s = tid + 512 * i;
    int row = s >> 3, c = (s & 7) * 8;
    *(int4*)(&Qs[row * LP + c]) = *(const int4*)(Qb + row * 64 + c);
  }
  __syncthreads();  // Q staged; tile-0 DMA drained -> buf0 ready
  bf16x8 qf[2];
#pragma unroll
  for (int ks = 0; ks < 2; ++ks)
    qf[ks] = *(const bf16x8*)(&Qs[(wave * 16 + fr) * LP + ks * 32 + q4 * 8]);
  __syncthreads();  // all waves' qf reads done -> Q region (buf1) free

  float l_i = 0.f;        // per-lane partial over this lane's 16 keys/iter
  f32x4 accO[4] = {};     // C-layout: row=qrow(q4*4+r), col=d(dt*16+fr)

  auto compute_tile = [&](const __bf16* Kbuf, const __bf16* Vbuf) {
    // S^T = K.Q^T: scT[nt][r] = P[qrow=wave*16+fr][key=nt*16+q4*4+r]
    f32x4 scT[4];
    __builtin_amdgcn_s_setprio(1);
#pragma unroll
    for (int nt = 0; nt < 4; ++nt) {
      bf16x8 kf0 = *(const bf16x8*)(&Kbuf[(nt * 16 + fr) * 64 + sx0]);
      bf16x8 kf1 = *(const bf16x8*)(&Kbuf[(nt * 16 + fr) * 64 + sx1]);
      f32x4 z = {};
      z = MFMA16(kf0, qf[0], z);
      scT[nt] = MFMA16(kf1, qf[1], z);
    }
    __builtin_amdgcn_s_setprio(0);
    // p = 2^s (bare v_exp_f32); per-lane l partial
    float rs = 0.f;
#pragma unroll
    for (int nt = 0; nt < 4; ++nt)
#pragma unroll
      for (int r = 0; r < 4; ++r) {
        float p = EXP2(scT[nt][r]);
        scT[nt][r] = p;
        rs += p;
      }
    l_i += rs;
    // O += P.V — P A-fragments are this lane's own registers under sigma
#pragma unroll
    for (int ks = 0; ks < 2; ++ks) {
      bf16x8 pf;
#pragma unroll
      for (int e = 0; e < 4; ++e) {
        pf[e] = to_bf16(scT[2 * ks][e]);
        pf[4 + e] = to_bf16(scT[2 * ks + 1][e]);
      }
      __builtin_amdgcn_s_setprio(1);
#pragma unroll
      for (int dt = 0; dt < 4; ++dt) {
        bf16x8 vf = *(const bf16x8*)(
            &Vbuf[(dt * 16 + fr) * 64 + (ks ? sx1 : sx0)]);
        accO[dt] = MFMA16(pf, vf, accO[dt]);
      }
      __builtin_amdgcn_s_setprio(0);
    }
  };

  for (int kt2 = 0; kt2 < 16; kt2 += 2) {
    // even phase: DMA tile kt2+1 -> buf1; compute tile kt2 from buf0
    gload16(ksrc + (size_t)(kt2 + 1) * 4096, kd1);
    gload16(vsrc + (size_t)(kt2 + 1) * 4096, vd1);
    compute_tile(K0, V0);
    __syncthreads();
    // odd phase: DMA tile kt2+2 -> buf0; compute tile kt2+1 from buf1
    if (kt2 + 2 < 16) {
      gload16(ksrc + (size_t)(kt2 + 2) * 4096, kd0);
      gload16(vsrc + (size_t)(kt2 + 2) * 4096, vd0);
    }
    compute_tile(K1, V1);
    __syncthreads();
  }

  // l: reduce across the 4 quads -> full sum per fr; then broadcast to rows.
  l_i += __shfl_xor(l_i, 16, 64);
  l_i += __shfl_xor(l_i, 32, 64);
  float lrow[4];
#pragma unroll
  for (int r = 0; r < 4; ++r) lrow[r] = __shfl(l_i, q4 * 4 + r, 64);

  const int h = bh % 12, bb = bh / 12;
#pragma unroll
  for (int dt = 0; dt < 4; ++dt)
#pragma unroll
    for (int r = 0; r < 4; ++r) {
      int row = bb * 1024 + qt * 128 + wave * 16 + q4 * 4 + r;
      int col = h * 64 + dt * 16 + fr;
      O[(size_t)row * 768 + col] = __float2bfloat16(accO[dt][r] / lrow[r]);
    }
}

// ---------------------------------------------------------------- launch
extern "C" void kernel_launch(void* const* d_in, const int* in_sizes, int n_in,
                              void* d_out, int out_size, void* d_ws, size_t ws_size,
                              hipStream_t stream) {
  const float* x     = (const float*)d_in[0];  // [8192][768]
  const float* Wqkv  = (const float*)d_in[1];  // [768][2304]
  const float* bqkv  = (const float*)d_in[2];  // [2304]
  const float* Wproj = (const float*)d_in[3];  // [768][768]
  const float* bproj = (const float*)d_in[4];  // [768]
  float* out = (float*)d_out;                  // [8192][768] fp32

  constexpr size_t NEEDED = 55050240;
  if (ws_size < NEEDED) {
    ws_diag_kernel<<<(out_size + 255) / 256, 256, 0, stream>>>(
        out, out_size, (float)(ws_size >> 20));
    return;
  }

  char* ws = (char*)d_ws;
  __hip_bfloat16* WqkvT  = (__hip_bfloat16*)(ws);               // 3,538,944 B
  __hip_bfloat16* WprojT = (__hip_bfloat16*)(ws + 3538944);     // 1,179,648 B
  __hip_bfloat16* Qw     = (__hip_bfloat16*)(ws + 4718592);     // 12,582,912 B
  __hip_bfloat16* Kw     = (__hip_bfloat16*)(ws + 17301504);    // 12,582,912 B
  __hip_bfloat16* Vrow   = (__hip_bfloat16*)(ws + 29884416);    // 12,582,912 B
  __hip_bfloat16* xc     = (__hip_bfloat16*)(ws + 42467328);    // 12,582,912 B
  __hip_bfloat16* Vsig   = xc;    // xc dead after gemm_qkv
  __hip_bfloat16* attnO  = Vrow;  // Vrow dead after vtrans
  // end = 55,050,240 (proven available)

  prep_kernel<<<5376, 256, 0, stream>>>(x, xc, Wqkv, WqkvT, Wproj, WprojT);
  gemm_qkv_kernel<<<dim3(64, 18), 256, 0, stream>>>(xc, WqkvT, bqkv, Qw, Kw, Vrow);
  vtrans_kernel<<<dim3(96, 16), 256, 0, stream>>>(Vrow, Vsig);
  attn_kernel<<<dim3(96 * 8), 512, 0, stream>>>(Qw, Kw, Vsig, attnO);
  gemm_proj_kernel<<<dim3(64, 6), 256, 0, stream>>>(attnO, WprojT, bproj, out);
}

// Round 13
// 180.452 us; speedup vs baseline: 1.0965x; 1.0328x over previous
//
#include <hip/hip_runtime.h>
#include <hip/hip_bf16.h>

// MHA forward. Inputs fp32, output fp32, compute bf16 MFMA w/ fp32 accum.
// B=8, N=1024, DIM=768, NH=12, HD=64, M=8192.
// R24: BISECT of R23's correctness failure (absmax 1.54e-3; two changes
// were made at once -- methodology error). This round: attn/vtrans/prep
// are R22-EXACT (proven 186.4us config); ONLY the GEMMs carry R23's
// pipelined dbuf (manual 2x unroll, literal buffer pointers, one rolling
// global pointer, stage(t+1)->other buf / compute(t) / ONE barrier --
// the guide's T3 minimum-2-phase recipe, refcheck'd in m230).
// If FAIL -> dbuf GEMM has a real race: close family, resubmit R22+attn.
// If PASS -> R23's attn rework was the bug; read qkv dur/VALUBusy to
// judge dbuf perf (R20's remat gave 42% VALU / 52us; literal pointers
// should avoid it).
// R22 carried: K and V staged via global_load_lds (rule 21: K source
// pre-swizzled, V sigma+swizzle pre-baked by vtrans into Vsig), XOR'd
// fragment reads sx0/sx1. R11 epilogues, fused prep, XCD swizzle bh=bx%96,
// bare v_exp_f32, S^T operand swap, deferred l-reduction, setprio (T5).
// WS high-water 55,050,240 B (proven available).

typedef __bf16 bf16x8 __attribute__((ext_vector_type(8)));
typedef float f32x4 __attribute__((ext_vector_type(4)));

#define MFMA16(a, b, c) __builtin_amdgcn_mfma_f32_16x16x32_bf16(a, b, c, 0, 0, 0)

#if defined(__has_builtin) && __has_builtin(__builtin_amdgcn_exp2f)
#define EXP2(x) __builtin_amdgcn_exp2f(x)
#else
#define EXP2(x) exp2f(x)
#endif

__device__ inline __bf16 to_bf16(float f) {
  __hip_bfloat16 h = __float2bfloat16(f);
  return *reinterpret_cast<__bf16*>(&h);
}

// Direct global->LDS DMA, 16B per lane. LDS dest is wave-uniform base + lane*16.
__device__ __forceinline__ void gload16(const void* g, void* l) {
  __builtin_amdgcn_global_load_lds(
      (const __attribute__((address_space(1))) unsigned int*)(unsigned long long)g,
      (__attribute__((address_space(3))) unsigned int*)(unsigned long long)l,
      16, 0, 0);
}

// ---------------------------------------------------------------- diagnostic
__global__ void ws_diag_kernel(float* out, int n, float val) {
  int i = blockIdx.x * 256 + threadIdx.x;
  if (i < n) out[i] = val;
}

// ---------------------------------------------------------------- fused prep
// blocks [0,3072): x fp32 -> xc bf16 (8 elems/thread)
// blocks [3072,4800): Wqkv [768][2304] -> WqkvT [2304][768] bf16 (72x24 tiles)
// blocks [4800,5376): Wproj [768][768] -> WprojT [768][768] bf16 (24x24 tiles)
__global__ __launch_bounds__(256) void prep_kernel(
    const float* __restrict__ x, __hip_bfloat16* __restrict__ xc,
    const float* __restrict__ Wqkv, __hip_bfloat16* __restrict__ WqkvT,
    const float* __restrict__ Wproj, __hip_bfloat16* __restrict__ WprojT) {
  __shared__ __hip_bfloat16 tile[32][33];
  const int b = blockIdx.x;
  if (b < 3072) {
    int i = b * 256 + threadIdx.x;
    float4 a = ((const float4*)x)[i * 2], c = ((const float4*)x)[i * 2 + 1];
    __hip_bfloat16 o[8] = {__float2bfloat16(a.x), __float2bfloat16(a.y),
                           __float2bfloat16(a.z), __float2bfloat16(a.w),
                           __float2bfloat16(c.x), __float2bfloat16(c.y),
                           __float2bfloat16(c.z), __float2bfloat16(c.w)};
    *(int4*)(xc + (size_t)i * 8) = *(const int4*)o;
    return;
  }
  const float* W;
  __hip_bfloat16* Wt;
  int rows, cols, bx, by;
  if (b < 4800) {
    int idx = b - 3072;  // 72 x 24 tile grid
    W = Wqkv; Wt = WqkvT; rows = 768; cols = 2304;
    bx = idx % 72; by = idx / 72;
  } else {
    int idx = b - 4800;  // 24 x 24 tile grid
    W = Wproj; Wt = WprojT; rows = 768; cols = 768;
    bx = idx % 24; by = idx / 24;
  }
  const int tc = bx * 32, tr = by * 32;
  const int tx = threadIdx.x & 31, ty = threadIdx.x >> 5;  // (32,8)
#pragma unroll
  for (int i = 0; i < 4; ++i) {
    int r = ty + i * 8;
    tile[r][tx] = __float2bfloat16(W[(size_t)(tr + r) * cols + tc + tx]);
  }
  __syncthreads();
#pragma unroll
  for (int i = 0; i < 4; ++i) {
    int r = ty + i * 8;
    Wt[(size_t)(tc + r) * rows + tr + tx] = tile[tx][r];
  }
}

// ---------------------------------------------------------------- V transpose
// Vrow [96][1024][64] -> Vsig [96][16 kt][64 d][64]: position p=sigma(key)
// at in-row addr ((p>>3)^(d&7))*8 + (p&7). Pieces int2 (8B-aligned), all
// within one 128B row (write-combines fully).
__global__ __launch_bounds__(256) void vtrans_kernel(
    const __hip_bfloat16* __restrict__ Vrow, __hip_bfloat16* __restrict__ Vsig) {
  constexpr int LP = 72;
  __shared__ __bf16 tile[64 * LP];
  const int tid = threadIdx.x;
  const int bh = blockIdx.x;
  const int n0 = blockIdx.y * 64;  // kt = blockIdx.y
  const size_t base = (size_t)bh << 16;
#pragma unroll
  for (int i = 0; i < 2; ++i) {
    int s = tid + 256 * i;
    int r = s >> 3, c8 = (s & 7) * 8;
    *(int4*)(&tile[r * LP + c8]) =
        *(const int4*)(Vrow + base + (size_t)(n0 + r) * 64 + c8);
  }
  __syncthreads();
#pragma unroll
  for (int i = 0; i < 2; ++i) {
    int s = tid + 256 * i;
    int d = s >> 3, c = s & 7;
    int n8 = c * 8;
    __bf16 o[8];
#pragma unroll
    for (int j = 0; j < 8; ++j) o[j] = tile[(n8 + j) * LP + d];
    int sb = ((c >> 2) << 5) | ((c & 1) << 4) | (((c >> 1) & 1) << 2);
    int x = d & 7;
    int a0 = (((sb >> 3) ^ x) << 3) | (sb & 7);
    int a1 = ((((sb >> 3) + 1) ^ x) << 3) | (sb & 7);
    __hip_bfloat16* vr = Vsig + base + (size_t)blockIdx.y * 4096 + d * 64;
    *(int2*)(vr + a0) = *(const int2*)&o[0];
    *(int2*)(vr + a1) = *(const int2*)&o[4];
  }
}

// ---------------------------------------------------------------- GEMM common
constexpr int GK = 768;

// ---------------------------------------------------------------- QKV GEMM
// 128x128 tile, BK=32, 4 waves, LDS 2x16KB dbuf. Manual 2x unroll w/
// literal buffer pointers: stage(t+1)->other buf, compute(t), ONE barrier.
__global__ __launch_bounds__(256) void gemm_qkv_kernel(
    const __hip_bfloat16* __restrict__ A,    // xc bf16 [8192][768]
    const __hip_bfloat16* __restrict__ Bt,   // WqkvT [2304][768] bf16
    const float* __restrict__ bias,          // b_qkv fp32 [2304]
    __hip_bfloat16* __restrict__ Qw,         // [96][1024][64] (Q scaled log2e/8)
    __hip_bfloat16* __restrict__ Kw,         // [96][1024][64]
    __hip_bfloat16* __restrict__ Vw) {       // [96][1024][64] row-major
  __shared__ __align__(16) __bf16 As[2 * 4096];  // buf h at +h*4096
  __shared__ __align__(16) __bf16 Bs[2 * 4096];
  const int tid = threadIdx.x;
  const int lane = tid & 63, wave = tid >> 6;
  const int wr = wave >> 1, wc = wave & 1;
  const int m0 = blockIdx.x * 128, n0 = blockIdx.y * 128;
  const int fr = lane & 15, q4 = lane >> 4;

  const int r4 = lane >> 2, c8 = (lane & 3) * 8;
  const __hip_bfloat16* ga0 = A + (size_t)(m0 + wave * 32 + r4) * GK + c8;
  const __hip_bfloat16* gb0 = Bt + (size_t)(n0 + wave * 32 + r4) * GK + c8;
  __bf16* la0 = &As[wave * 1024];
  __bf16* lb0 = &Bs[wave * 1024];
  __bf16* la1 = la0 + 4096;
  __bf16* lb1 = lb0 + 4096;

  f32x4 acc[4][4] = {};

  auto stage = [&](const __hip_bfloat16* ga, const __hip_bfloat16* gb,
                   __bf16* la, __bf16* lb) {
    gload16(ga, la);
    gload16(ga + 16 * GK, la + 512);
    gload16(gb, lb);
    gload16(gb + 16 * GK, lb + 512);
  };
  auto compute = [&](int off) {
    bf16x8 af[4], bfr[4];
#pragma unroll
    for (int i = 0; i < 4; ++i)
      af[i] = *(const bf16x8*)(&As[off + (wr * 64 + i * 16 + fr) * 32 + q4 * 8]);
#pragma unroll
    for (int j = 0; j < 4; ++j)
      bfr[j] = *(const bf16x8*)(&Bs[off + (wc * 64 + j * 16 + fr) * 32 + q4 * 8]);
#pragma unroll
    for (int i = 0; i < 4; ++i)
#pragma unroll
      for (int j = 0; j < 4; ++j)
        acc[i][j] = MFMA16(af[i], bfr[j], acc[i][j]);
  };

  // prologue: tile 0 -> buf0
  stage(ga0, gb0, la0, lb0);
  __syncthreads();
  const __hip_bfloat16* gaN = ga0 + 32;  // tile 2it+1
  const __hip_bfloat16* gbN = gb0 + 32;
  for (int it = 0; it < 11; ++it) {
    stage(gaN, gbN, la1, lb1);        // tile 2it+1 -> buf1 (flies under compute)
    compute(0);                        // tile 2it from buf0
    __syncthreads();                   // drains stage; buf0 free
    stage(gaN + 32, gbN + 32, la0, lb0);  // tile 2it+2 -> buf0
    compute(4096);                     // tile 2it+1 from buf1
    __syncthreads();
    gaN += 64;
    gbN += 64;
  }
  // tail: buf0 holds tile 22; stage 23 -> buf1
  stage(gaN, gbN, la1, lb1);
  compute(0);
  __syncthreads();
  compute(4096);

#pragma unroll
  for (int j = 0; j < 4; ++j) {
    int col = n0 + wc * 64 + j * 16 + fr;
    int which = col / 768;
    int rem = col - which * 768;
    int h = rem >> 6, d = rem & 63;
    float bv = bias[col];
    __hip_bfloat16* dst = (which == 0) ? Qw : (which == 1) ? Kw : Vw;
    // Q scale = 1/sqrt(64) * log2(e), so attention can use raw exp2.
    float scale = (which == 0) ? 0.18033688011112042f : 1.0f;
#pragma unroll
    for (int i = 0; i < 4; ++i) {
#pragma unroll
      for (int r = 0; r < 4; ++r) {
        int row = m0 + wr * 64 + i * 16 + q4 * 4 + r;
        int bb = row >> 10, nn = row & 1023;
        float v = (acc[i][j][r] + bv) * scale;
        dst[(((size_t)(bb * 12 + h) * 1024 + nn) << 6) + d] = __float2bfloat16(v);
      }
    }
  }
}

// ---------------------------------------------------------------- proj GEMM
__global__ __launch_bounds__(256) void gemm_proj_kernel(
    const __hip_bfloat16* __restrict__ A,   // attnO bf16 [8192][768]
    const __hip_bfloat16* __restrict__ Bt,  // WprojT bf16 [768][768]
    const float* __restrict__ bias,         // b_proj fp32 [768]
    float* __restrict__ out) {              // d_out fp32 [8192][768]
  __shared__ __align__(16) __bf16 As[2 * 4096];
  __shared__ __align__(16) __bf16 Bs[2 * 4096];
  const int tid = threadIdx.x;
  const int lane = tid & 63, wave = tid >> 6;
  const int wr = wave >> 1, wc = wave & 1;
  const int m0 = blockIdx.x * 128, n0 = blockIdx.y * 128;
  const int fr = lane & 15, q4 = lane >> 4;

  const int r4 = lane >> 2, c8 = (lane & 3) * 8;
  const __hip_bfloat16* ga0 = A + (size_t)(m0 + wave * 32 + r4) * GK + c8;
  const __hip_bfloat16* gb0 = Bt + (size_t)(n0 + wave * 32 + r4) * GK + c8;
  __bf16* la0 = &As[wave * 1024];
  __bf16* lb0 = &Bs[wave * 1024];
  __bf16* la1 = la0 + 4096;
  __bf16* lb1 = lb0 + 4096;

  f32x4 acc[4][4] = {};

  auto stage = [&](const __hip_bfloat16* ga, const __hip_bfloat16* gb,
                   __bf16* la, __bf16* lb) {
    gload16(ga, la);
    gload16(ga + 16 * GK, la + 512);
    gload16(gb, lb);
    gload16(gb + 16 * GK, lb + 512);
  };
  auto compute = [&](int off) {
    bf16x8 af[4], bfr[4];
#pragma unroll
    for (int i = 0; i < 4; ++i)
      af[i] = *(const bf16x8*)(&As[off + (wr * 64 + i * 16 + fr) * 32 + q4 * 8]);
#pragma unroll
    for (int j = 0; j < 4; ++j)
      bfr[j] = *(const bf16x8*)(&Bs[off + (wc * 64 + j * 16 + fr) * 32 + q4 * 8]);
#pragma unroll
    for (int i = 0; i < 4; ++i)
#pragma unroll
      for (int j = 0; j < 4; ++j)
        acc[i][j] = MFMA16(af[i], bfr[j], acc[i][j]);
  };

  stage(ga0, gb0, la0, lb0);
  __syncthreads();
  const __hip_bfloat16* gaN = ga0 + 32;
  const __hip_bfloat16* gbN = gb0 + 32;
  for (int it = 0; it < 11; ++it) {
    stage(gaN, gbN, la1, lb1);
    compute(0);
    __syncthreads();
    stage(gaN + 32, gbN + 32, la0, lb0);
    compute(4096);
    __syncthreads();
    gaN += 64;
    gbN += 64;
  }
  stage(gaN, gbN, la1, lb1);
  compute(0);
  __syncthreads();
  compute(4096);

#pragma unroll
  for (int j = 0; j < 4; ++j) {
    int col = n0 + wc * 64 + j * 16 + fr;
    float bv = bias[col];
#pragma unroll
    for (int i = 0; i < 4; ++i) {
#pragma unroll
      for (int r = 0; r < 4; ++r) {
        int row = m0 + wr * 64 + i * 16 + q4 * 4 + r;
        out[(size_t)row * 768 + col] = acc[i][j][r] + bv;
      }
    }
  }
}

// ---------------------------------------------------------------- attention
// R22-EXACT. block = (b,h,128 q-rows); 8 waves x 16 qrows; KV tiles of 64.
// S^T = K.Q^T via operand swap; P stays in registers (sigma pre-baked in
// Vsig). K AND V staged via global_load_lds into linear 4KB-elem buffers;
// both read at XOR'd offsets sx0/sx1. One barrier per KV tile; DMA for
// tile t+1 issued before compute(t).
__global__ __launch_bounds__(512) void attn_kernel(
    const __hip_bfloat16* __restrict__ Qw,  // [96][1024][64], scaled log2e/8
    const __hip_bfloat16* __restrict__ Kw,  // [96][1024][64]
    const __hip_bfloat16* __restrict__ Vsig,// [96][16][64][64] sigma+swz
    __hip_bfloat16* __restrict__ O) {       // attnO [8192][768], col = h*64+d
  constexpr int LP = 72;
  // [0,8192): buf1 {K1@0, V1@4096}; Qs@0 (9216, overlaps buf1, dead after qf)
  // [9216,17408): buf0 {K0@9216, V0@13312}
  __shared__ __align__(16) __bf16 smem[17408];
  __bf16* Qs = smem;
  __bf16* K1 = smem;
  __bf16* V1 = smem + 4096;
  __bf16* K0 = smem + 9216;
  __bf16* V0 = smem + 13312;
  const int tid = threadIdx.x;
  const int lane = tid & 63, wave = tid >> 6;  // 8 waves
  const int fr = lane & 15, q4 = lane >> 4;
  const int bh = blockIdx.x % 96, qt = blockIdx.x / 96;  // XCD-local KV
  const __hip_bfloat16* Qb = Qw + ((size_t)bh * 1024 + qt * 128) * 64;
  const __hip_bfloat16* Kb = Kw + (size_t)bh * 65536;
  const __hip_bfloat16* Vb = Vsig + (size_t)bh * 65536;

  // staging addresses: K source pre-swizzled; V source linear (pre-baked).
  const int krow = tid >> 3;
  const int kchunk = ((tid & 7) ^ (krow & 7)) * 8;
  const __hip_bfloat16* ksrc = Kb + (size_t)krow * 64 + kchunk;  // + kt*4096
  const __hip_bfloat16* vsrc = Vb + (size_t)tid * 8;             // + kt*4096
  __bf16* kd0 = K0 + wave * 512;
  __bf16* kd1 = K1 + wave * 512;
  __bf16* vd0 = V0 + wave * 512;
  __bf16* vd1 = V1 + wave * 512;
  // XOR'd fragment-read offsets (shared by K and V: row&7 == fr&7)
  const int sx0 = (q4 ^ (fr & 7)) * 8;
  const int sx1 = sx0 ^ 32;

  // prolog: DMA tile 0 -> buf0 (covered by Q staging)
  gload16(ksrc, kd0);
  gload16(vsrc, vd0);

  // stage Q 128x64 (2 int4/thread)
#pragma unroll
  for (int i = 0; i < 2; ++i) {
    int s = tid + 512 * i;
    int row = s >> 3, c = (s & 7) * 8;
    *(int4*)(&Qs[row * LP + c]) = *(const int4*)(Qb + row * 64 + c);
  }
  __syncthreads();  // Q staged; tile-0 DMA drained -> buf0 ready
  bf16x8 qf[2];
#pragma unroll
  for (int ks = 0; ks < 2; ++ks)
    qf[ks] = *(const bf16x8*)(&Qs[(wave * 16 + fr) * LP + ks * 32 + q4 * 8]);
  __syncthreads();  // all waves' qf reads done -> Q region (buf1) free

  float l_i = 0.f;        // per-lane partial over this lane's 16 keys/iter
  f32x4 accO[4] = {};     // C-layout: row=qrow(q4*4+r), col=d(dt*16+fr)

  auto compute_tile = [&](const __bf16* Kbuf, const __bf16* Vbuf) {
    // S^T = K.Q^T: scT[nt][r] = P[qrow=wave*16+fr][key=nt*16+q4*4+r]
    f32x4 scT[4];
    __builtin_amdgcn_s_setprio(1);
#pragma unroll
    for (int nt = 0; nt < 4; ++nt) {
      bf16x8 kf0 = *(const bf16x8*)(&Kbuf[(nt * 16 + fr) * 64 + sx0]);
      bf16x8 kf1 = *(const bf16x8*)(&Kbuf[(nt * 16 + fr) * 64 + sx1]);
      f32x4 z = {};
      z = MFMA16(kf0, qf[0], z);
      scT[nt] = MFMA16(kf1, qf[1], z);
    }
    __builtin_amdgcn_s_setprio(0);
    // p = 2^s (bare v_exp_f32); per-lane l partial
    float rs = 0.f;
#pragma unroll
    for (int nt = 0; nt < 4; ++nt)
#pragma unroll
      for (int r = 0; r < 4; ++r) {
        float p = EXP2(scT[nt][r]);
        scT[nt][r] = p;
        rs += p;
      }
    l_i += rs;
    // O += P.V — P A-fragments are this lane's own registers under sigma
#pragma unroll
    for (int ks = 0; ks < 2; ++ks) {
      bf16x8 pf;
#pragma unroll
      for (int e = 0; e < 4; ++e) {
        pf[e] = to_bf16(scT[2 * ks][e]);
        pf[4 + e] = to_bf16(scT[2 * ks + 1][e]);
      }
      __builtin_amdgcn_s_setprio(1);
#pragma unroll
      for (int dt = 0; dt < 4; ++dt) {
        bf16x8 vf = *(const bf16x8*)(
            &Vbuf[(dt * 16 + fr) * 64 + (ks ? sx1 : sx0)]);
        accO[dt] = MFMA16(pf, vf, accO[dt]);
      }
      __builtin_amdgcn_s_setprio(0);
    }
  };

  for (int kt2 = 0; kt2 < 16; kt2 += 2) {
    // even phase: DMA tile kt2+1 -> buf1; compute tile kt2 from buf0
    gload16(ksrc + (size_t)(kt2 + 1) * 4096, kd1);
    gload16(vsrc + (size_t)(kt2 + 1) * 4096, vd1);
    compute_tile(K0, V0);
    __syncthreads();
    // odd phase: DMA tile kt2+2 -> buf0; compute tile kt2+1 from buf1
    if (kt2 + 2 < 16) {
      gload16(ksrc + (size_t)(kt2 + 2) * 4096, kd0);
      gload16(vsrc + (size_t)(kt2 + 2) * 4096, vd0);
    }
    compute_tile(K1, V1);
    __syncthreads();
  }

  // l: reduce across the 4 quads -> full sum per fr; then broadcast to rows.
  l_i += __shfl_xor(l_i, 16, 64);
  l_i += __shfl_xor(l_i, 32, 64);
  float lrow[4];
#pragma unroll
  for (int r = 0; r < 4; ++r) lrow[r] = __shfl(l_i, q4 * 4 + r, 64);

  const int h = bh % 12, bb = bh / 12;
#pragma unroll
  for (int dt = 0; dt < 4; ++dt)
#pragma unroll
    for (int r = 0; r < 4; ++r) {
      int row = bb * 1024 + qt * 128 + wave * 16 + q4 * 4 + r;
      int col = h * 64 + dt * 16 + fr;
      O[(size_t)row * 768 + col] = __float2bfloat16(accO[dt][r] / lrow[r]);
    }
}

// ---------------------------------------------------------------- launch
extern "C" void kernel_launch(void* const* d_in, const int* in_sizes, int n_in,
                              void* d_out, int out_size, void* d_ws, size_t ws_size,
                              hipStream_t stream) {
  const float* x     = (const float*)d_in[0];  // [8192][768]
  const float* Wqkv  = (const float*)d_in[1];  // [768][2304]
  const float* bqkv  = (const float*)d_in[2];  // [2304]
  const float* Wproj = (const float*)d_in[3];  // [768][768]
  const float* bproj = (const float*)d_in[4];  // [768]
  float* out = (float*)d_out;                  // [8192][768] fp32

  constexpr size_t NEEDED = 55050240;
  if (ws_size < NEEDED) {
    ws_diag_kernel<<<(out_size + 255) / 256, 256, 0, stream>>>(
        out, out_size, (float)(ws_size >> 20));
    return;
  }

  char* ws = (char*)d_ws;
  __hip_bfloat16* WqkvT  = (__hip_bfloat16*)(ws);               // 3,538,944 B
  __hip_bfloat16* WprojT = (__hip_bfloat16*)(ws + 3538944);     // 1,179,648 B
  __hip_bfloat16* Qw     = (__hip_bfloat16*)(ws + 4718592);     // 12,582,912 B
  __hip_bfloat16* Kw     = (__hip_bfloat16*)(ws + 17301504);    // 12,582,912 B
  __hip_bfloat16* Vrow   = (__hip_bfloat16*)(ws + 29884416);    // 12,582,912 B
  __hip_bfloat16* xc     = (__hip_bfloat16*)(ws + 42467328);    // 12,582,912 B
  __hip_bfloat16* Vsig   = xc;    // xc dead after gemm_qkv
  __hip_bfloat16* attnO  = Vrow;  // Vrow dead after vtrans
  // end = 55,050,240 (proven available)

  prep_kernel<<<5376, 256, 0, stream>>>(x, xc, Wqkv, WqkvT, Wproj, WprojT);
  gemm_qkv_kernel<<<dim3(64, 18), 256, 0, stream>>>(xc, WqkvT, bqkv, Qw, Kw, Vrow);
  vtrans_kernel<<<dim3(96, 16), 256, 0, stream>>>(Vrow, Vsig);
  attn_kernel<<<dim3(96 * 8), 512, 0, stream>>>(Qw, Kw, Vsig, attnO);
  gemm_proj_kernel<<<dim3(64, 6), 256, 0, stream>>>(attnO, WprojT, bproj, out);
}